// Round 1
// baseline (1583.922 us; speedup 1.0000x reference)
//
#include <hip/hip_runtime.h>

#define NFEAT 128

// ---------------------------------------------------------------------------
// K1: msg = edge_att * node_att[src]; agg[dst] += msg   (scatter-add)
// One 32-lane group per edge; each lane owns a float4 column chunk.
// ---------------------------------------------------------------------------
__global__ void scatter_msg_kernel(const float* __restrict__ node_att,
                                   const float* __restrict__ edge_att,
                                   const int* __restrict__ src,
                                   const int* __restrict__ dst,
                                   float* __restrict__ agg,
                                   int n_edges) {
    int t = blockIdx.x * blockDim.x + threadIdx.x;
    int e = t >> 5;                 // edge index
    int c = (t & 31) << 2;          // feature column (float4 chunk)
    if (e >= n_edges) return;

    int s = src[e];
    int d = dst[e];

    const float4 ea = *reinterpret_cast<const float4*>(edge_att + (size_t)e * NFEAT + c);
    const float4 na = *reinterpret_cast<const float4*>(node_att + (size_t)s * NFEAT + c);

    float* out = agg + (size_t)d * NFEAT + c;
    atomicAdd(out + 0, ea.x * na.x);
    atomicAdd(out + 1, ea.y * na.y);
    atomicAdd(out + 2, ea.z * na.z);
    atomicAdd(out + 3, ea.w * na.w);
}

// ---------------------------------------------------------------------------
// K2: new_node_att = softmax(agg + node_att, axis=1)
// One 32-lane group per node row; float4 per lane; shuffle-reduce (width 32).
// ---------------------------------------------------------------------------
__global__ void node_softmax_kernel(const float* __restrict__ agg,
                                    const float* __restrict__ node_att,
                                    float* __restrict__ out,
                                    int n_nodes) {
    int t = blockIdx.x * blockDim.x + threadIdx.x;
    int r = t >> 5;
    int c = (t & 31) << 2;
    if (r >= n_nodes) return;

    size_t base = (size_t)r * NFEAT + c;
    float4 a = *reinterpret_cast<const float4*>(agg + base);
    float4 b = *reinterpret_cast<const float4*>(node_att + base);
    float4 v;
    v.x = a.x + b.x; v.y = a.y + b.y; v.z = a.z + b.z; v.w = a.w + b.w;

    // row max
    float m = fmaxf(fmaxf(v.x, v.y), fmaxf(v.z, v.w));
    #pragma unroll
    for (int off = 16; off > 0; off >>= 1)
        m = fmaxf(m, __shfl_xor(m, off, 32));

    v.x = __expf(v.x - m); v.y = __expf(v.y - m);
    v.z = __expf(v.z - m); v.w = __expf(v.w - m);

    float s = v.x + v.y + v.z + v.w;
    #pragma unroll
    for (int off = 16; off > 0; off >>= 1)
        s += __shfl_xor(s, off, 32);

    float inv = 1.0f / s;
    v.x *= inv; v.y *= inv; v.z *= inv; v.w *= inv;
    *reinterpret_cast<float4*>(out + base) = v;
}

// ---------------------------------------------------------------------------
// K3: new_edge_att = softmax(new_node[src]*new_node[dst] + edge_att, axis=1)
// One 32-lane group per edge row.
// ---------------------------------------------------------------------------
__global__ void edge_softmax_kernel(const float* __restrict__ new_node,
                                    const float* __restrict__ edge_att,
                                    const int* __restrict__ src,
                                    const int* __restrict__ dst,
                                    float* __restrict__ out,
                                    int n_edges) {
    int t = blockIdx.x * blockDim.x + threadIdx.x;
    int e = t >> 5;
    int c = (t & 31) << 2;
    if (e >= n_edges) return;

    int s_i = src[e];
    int d_i = dst[e];

    float4 ns = *reinterpret_cast<const float4*>(new_node + (size_t)s_i * NFEAT + c);
    float4 nd = *reinterpret_cast<const float4*>(new_node + (size_t)d_i * NFEAT + c);
    float4 ea = *reinterpret_cast<const float4*>(edge_att + (size_t)e * NFEAT + c);

    float4 v;
    v.x = ns.x * nd.x + ea.x;
    v.y = ns.y * nd.y + ea.y;
    v.z = ns.z * nd.z + ea.z;
    v.w = ns.w * nd.w + ea.w;

    float m = fmaxf(fmaxf(v.x, v.y), fmaxf(v.z, v.w));
    #pragma unroll
    for (int off = 16; off > 0; off >>= 1)
        m = fmaxf(m, __shfl_xor(m, off, 32));

    v.x = __expf(v.x - m); v.y = __expf(v.y - m);
    v.z = __expf(v.z - m); v.w = __expf(v.w - m);

    float s = v.x + v.y + v.z + v.w;
    #pragma unroll
    for (int off = 16; off > 0; off >>= 1)
        s += __shfl_xor(s, off, 32);

    float inv = 1.0f / s;
    v.x *= inv; v.y *= inv; v.z *= inv; v.w *= inv;
    *reinterpret_cast<float4*>(out + (size_t)e * NFEAT + c) = v;
}

// ---------------------------------------------------------------------------
extern "C" void kernel_launch(void* const* d_in, const int* in_sizes, int n_in,
                              void* d_out, int out_size, void* d_ws, size_t ws_size,
                              hipStream_t stream) {
    const float* node_att = (const float*)d_in[0];
    const float* edge_att = (const float*)d_in[1];
    const int*   src      = (const int*)d_in[2];
    const int*   dst      = (const int*)d_in[3];

    int n_nodes = in_sizes[0] / NFEAT;
    int n_edges = in_sizes[2];

    float* out_node = (float*)d_out;                         // [N, 128]
    float* out_edge = out_node + (size_t)n_nodes * NFEAT;    // [E, 128]
    float* agg      = (float*)d_ws;                          // [N, 128] scratch

    // zero the aggregation buffer (must be per-call: harness doesn't re-poison)
    hipMemsetAsync(agg, 0, (size_t)n_nodes * NFEAT * sizeof(float), stream);

    const int BLK = 256;

    // K1: one 32-lane group per edge
    {
        long long threads = (long long)n_edges * 32;
        int grid = (int)((threads + BLK - 1) / BLK);
        scatter_msg_kernel<<<grid, BLK, 0, stream>>>(node_att, edge_att, src, dst,
                                                     agg, n_edges);
    }
    // K2: one 32-lane group per node
    {
        long long threads = (long long)n_nodes * 32;
        int grid = (int)((threads + BLK - 1) / BLK);
        node_softmax_kernel<<<grid, BLK, 0, stream>>>(agg, node_att, out_node, n_nodes);
    }
    // K3: one 32-lane group per edge
    {
        long long threads = (long long)n_edges * 32;
        int grid = (int)((threads + BLK - 1) / BLK);
        edge_softmax_kernel<<<grid, BLK, 0, stream>>>(out_node, edge_att, src, dst,
                                                      out_edge, n_edges);
    }
}

// Round 2
// 510.341 us; speedup vs baseline: 3.1037x; 3.1037x over previous
//
#include <hip/hip_runtime.h>

#define NFEAT 128

// ---------------------------------------------------------------------------
// CSR build pass A: histogram of dst
// ---------------------------------------------------------------------------
__global__ void hist_kernel(const int* __restrict__ dst,
                            int* __restrict__ counts, int n_edges) {
    int e = blockIdx.x * blockDim.x + threadIdx.x;
    if (e < n_edges) atomicAdd(&counts[dst[e]], 1);
}

// ---------------------------------------------------------------------------
// CSR build pass B: exclusive prefix scan (single 1024-thread block).
// Wave-level shuffle scan + cross-wave LDS scan; ~49 chunks of 1024.
// Writes offsets[0..n] and a second copy (cursor) for the fill pass.
// ---------------------------------------------------------------------------
__global__ void scan_kernel(const int* __restrict__ counts,
                            int* __restrict__ offsets,
                            int* __restrict__ cursor, int n) {
    __shared__ int wsum[16];
    __shared__ int carry_s;
    int tid  = threadIdx.x;
    int lane = tid & 63;
    int wid  = tid >> 6;
    if (tid == 0) carry_s = 0;
    __syncthreads();

    for (int base = 0; base < n; base += 1024) {
        int i = base + tid;
        int v = (i < n) ? counts[i] : 0;

        // inclusive scan within wave (64 lanes)
        int x = v;
        #pragma unroll
        for (int off = 1; off < 64; off <<= 1) {
            int y = __shfl_up(x, off, 64);
            if (lane >= off) x += y;
        }
        if (lane == 63) wsum[wid] = x;
        __syncthreads();

        // scan the 16 wave totals (lanes 0..15 of wave 0)
        if (tid < 16) {
            int w = wsum[tid];
            #pragma unroll
            for (int off = 1; off < 16; off <<= 1) {
                int y = __shfl_up(w, off, 16);
                if (tid >= off) w += y;
            }
            wsum[tid] = w;   // inclusive sums of wave totals
        }
        __syncthreads();

        int waveoff = (wid == 0) ? 0 : wsum[wid - 1];
        int carry   = carry_s;
        int excl    = carry + waveoff + x - v;
        if (i < n) { offsets[i] = excl; cursor[i] = excl; }
        __syncthreads();
        if (tid == 1023) carry_s = carry + waveoff + x;  // chunk total
        __syncthreads();
    }
    if (tid == 0) offsets[n] = carry_s;
}

// ---------------------------------------------------------------------------
// CSR build pass C: fill edge id lists (int atomics on 200 KB cursor array)
// ---------------------------------------------------------------------------
__global__ void fill_kernel(const int* __restrict__ dst,
                            int* __restrict__ cursor,
                            int* __restrict__ edge_ids, int n_edges) {
    int e = blockIdx.x * blockDim.x + threadIdx.x;
    if (e < n_edges) {
        int pos = atomicAdd(&cursor[dst[e]], 1);
        edge_ids[pos] = e;
    }
}

// ---------------------------------------------------------------------------
// Fused segment-sum + node softmax:
// new_node[r] = softmax(node_att[r] + sum_{e: dst[e]==r} edge_att[e]*node_att[src[e]])
// One 32-lane group per node row; lane owns a float4 column chunk.
// ---------------------------------------------------------------------------
__global__ void node_gather_softmax_kernel(const float* __restrict__ node_att,
                                           const float* __restrict__ edge_att,
                                           const int* __restrict__ src,
                                           const int* __restrict__ offsets,
                                           const int* __restrict__ edge_ids,
                                           float* __restrict__ out, int n_nodes) {
    int t = blockIdx.x * blockDim.x + threadIdx.x;
    int r = t >> 5;
    int c = (t & 31) << 2;
    if (r >= n_nodes) return;

    size_t base = (size_t)r * NFEAT + c;
    float4 acc = *reinterpret_cast<const float4*>(node_att + base);

    int beg = offsets[r];
    int end = offsets[r + 1];
    for (int i = beg; i < end; ++i) {
        int e = edge_ids[i];
        int s = src[e];
        float4 ea = *reinterpret_cast<const float4*>(edge_att + (size_t)e * NFEAT + c);
        float4 na = *reinterpret_cast<const float4*>(node_att + (size_t)s * NFEAT + c);
        acc.x += ea.x * na.x;
        acc.y += ea.y * na.y;
        acc.z += ea.z * na.z;
        acc.w += ea.w * na.w;
    }

    // softmax over the 128-feature row
    float m = fmaxf(fmaxf(acc.x, acc.y), fmaxf(acc.z, acc.w));
    #pragma unroll
    for (int off = 16; off > 0; off >>= 1)
        m = fmaxf(m, __shfl_xor(m, off, 32));

    acc.x = __expf(acc.x - m); acc.y = __expf(acc.y - m);
    acc.z = __expf(acc.z - m); acc.w = __expf(acc.w - m);

    float s = acc.x + acc.y + acc.z + acc.w;
    #pragma unroll
    for (int off = 16; off > 0; off >>= 1)
        s += __shfl_xor(s, off, 32);

    float inv = 1.0f / s;
    acc.x *= inv; acc.y *= inv; acc.z *= inv; acc.w *= inv;
    *reinterpret_cast<float4*>(out + base) = acc;
}

// ---------------------------------------------------------------------------
// K3: new_edge_att = softmax(new_node[src]*new_node[dst] + edge_att, axis=1)
// ---------------------------------------------------------------------------
__global__ void edge_softmax_kernel(const float* __restrict__ new_node,
                                    const float* __restrict__ edge_att,
                                    const int* __restrict__ src,
                                    const int* __restrict__ dst,
                                    float* __restrict__ out, int n_edges) {
    int t = blockIdx.x * blockDim.x + threadIdx.x;
    int e = t >> 5;
    int c = (t & 31) << 2;
    if (e >= n_edges) return;

    int s_i = src[e];
    int d_i = dst[e];

    float4 ns = *reinterpret_cast<const float4*>(new_node + (size_t)s_i * NFEAT + c);
    float4 nd = *reinterpret_cast<const float4*>(new_node + (size_t)d_i * NFEAT + c);
    float4 ea = *reinterpret_cast<const float4*>(edge_att + (size_t)e * NFEAT + c);

    float4 v;
    v.x = ns.x * nd.x + ea.x;
    v.y = ns.y * nd.y + ea.y;
    v.z = ns.z * nd.z + ea.z;
    v.w = ns.w * nd.w + ea.w;

    float m = fmaxf(fmaxf(v.x, v.y), fmaxf(v.z, v.w));
    #pragma unroll
    for (int off = 16; off > 0; off >>= 1)
        m = fmaxf(m, __shfl_xor(m, off, 32));

    v.x = __expf(v.x - m); v.y = __expf(v.y - m);
    v.z = __expf(v.z - m); v.w = __expf(v.w - m);

    float s = v.x + v.y + v.z + v.w;
    #pragma unroll
    for (int off = 16; off > 0; off >>= 1)
        s += __shfl_xor(s, off, 32);

    float inv = 1.0f / s;
    v.x *= inv; v.y *= inv; v.z *= inv; v.w *= inv;
    *reinterpret_cast<float4*>(out + (size_t)e * NFEAT + c) = v;
}

// ---------------------------------------------------------------------------
extern "C" void kernel_launch(void* const* d_in, const int* in_sizes, int n_in,
                              void* d_out, int out_size, void* d_ws, size_t ws_size,
                              hipStream_t stream) {
    const float* node_att = (const float*)d_in[0];
    const float* edge_att = (const float*)d_in[1];
    const int*   src      = (const int*)d_in[2];
    const int*   dst      = (const int*)d_in[3];

    int n_nodes = in_sizes[0] / NFEAT;
    int n_edges = in_sizes[2];

    float* out_node = (float*)d_out;                       // [N, 128]
    float* out_edge = out_node + (size_t)n_nodes * NFEAT;  // [E, 128]

    // workspace layout (ints): counts[N] | offsets[N+1] | cursor[N] | edge_ids[E]
    int* counts   = (int*)d_ws;
    int* offsets  = counts + n_nodes;
    int* cursor   = offsets + (n_nodes + 1);
    int* edge_ids = cursor + n_nodes;

    const int BLK = 256;

    // zero histogram (must be per-call)
    hipMemsetAsync(counts, 0, (size_t)n_nodes * sizeof(int), stream);

    // CSR build
    {
        int grid = (n_edges + BLK - 1) / BLK;
        hist_kernel<<<grid, BLK, 0, stream>>>(dst, counts, n_edges);
    }
    scan_kernel<<<1, 1024, 0, stream>>>(counts, offsets, cursor, n_nodes);
    {
        int grid = (n_edges + BLK - 1) / BLK;
        fill_kernel<<<grid, BLK, 0, stream>>>(dst, cursor, edge_ids, n_edges);
    }

    // fused segment-sum + node softmax
    {
        long long threads = (long long)n_nodes * 32;
        int grid = (int)((threads + BLK - 1) / BLK);
        node_gather_softmax_kernel<<<grid, BLK, 0, stream>>>(
            node_att, edge_att, src, offsets, edge_ids, out_node, n_nodes);
    }
    // edge softmax
    {
        long long threads = (long long)n_edges * 32;
        int grid = (int)((threads + BLK - 1) / BLK);
        edge_softmax_kernel<<<grid, BLK, 0, stream>>>(
            out_node, edge_att, src, dst, out_edge, n_edges);
    }
}

// Round 3
// 509.991 us; speedup vs baseline: 3.1058x; 1.0007x over previous
//
#include <hip/hip_runtime.h>

#define NFEAT 128

// ---------------------------------------------------------------------------
// Zero the counts array (replaces pathologically-slow hipMemsetAsync fill).
// ---------------------------------------------------------------------------
__global__ void zero_kernel(int* __restrict__ p, int n) {
    int i = blockIdx.x * blockDim.x + threadIdx.x;
    if (i < n) p[i] = 0;
}

// ---------------------------------------------------------------------------
// CSR build pass A: histogram of dst
// ---------------------------------------------------------------------------
__global__ void hist_kernel(const int* __restrict__ dst,
                            int* __restrict__ counts, int n_edges) {
    int e = blockIdx.x * blockDim.x + threadIdx.x;
    if (e < n_edges) atomicAdd(&counts[dst[e]], 1);
}

// ---------------------------------------------------------------------------
// CSR build pass B: exclusive prefix scan (single 1024-thread block).
// ---------------------------------------------------------------------------
__global__ void scan_kernel(const int* __restrict__ counts,
                            int* __restrict__ offsets,
                            int* __restrict__ cursor, int n) {
    __shared__ int wsum[16];
    __shared__ int carry_s;
    int tid  = threadIdx.x;
    int lane = tid & 63;
    int wid  = tid >> 6;
    if (tid == 0) carry_s = 0;
    __syncthreads();

    for (int base = 0; base < n; base += 1024) {
        int i = base + tid;
        int v = (i < n) ? counts[i] : 0;

        int x = v;
        #pragma unroll
        for (int off = 1; off < 64; off <<= 1) {
            int y = __shfl_up(x, off, 64);
            if (lane >= off) x += y;
        }
        if (lane == 63) wsum[wid] = x;
        __syncthreads();

        if (tid < 16) {
            int w = wsum[tid];
            #pragma unroll
            for (int off = 1; off < 16; off <<= 1) {
                int y = __shfl_up(w, off, 16);
                if (tid >= off) w += y;
            }
            wsum[tid] = w;
        }
        __syncthreads();

        int waveoff = (wid == 0) ? 0 : wsum[wid - 1];
        int carry   = carry_s;
        int excl    = carry + waveoff + x - v;
        if (i < n) { offsets[i] = excl; cursor[i] = excl; }
        __syncthreads();
        if (tid == 1023) carry_s = carry + waveoff + x;
        __syncthreads();
    }
    if (tid == 0) offsets[n] = carry_s;
}

// ---------------------------------------------------------------------------
// CSR build pass C: fill edge id lists
// ---------------------------------------------------------------------------
__global__ void fill_kernel(const int* __restrict__ dst,
                            int* __restrict__ cursor,
                            int* __restrict__ edge_ids, int n_edges) {
    int e = blockIdx.x * blockDim.x + threadIdx.x;
    if (e < n_edges) {
        int pos = atomicAdd(&cursor[dst[e]], 1);
        edge_ids[pos] = e;
    }
}

// ---------------------------------------------------------------------------
// Fused segment-sum + node softmax.
// One 32-lane group per node row; lane owns a float4 column chunk.
// ---------------------------------------------------------------------------
__global__ void node_gather_softmax_kernel(const float* __restrict__ node_att,
                                           const float* __restrict__ edge_att,
                                           const int* __restrict__ src,
                                           const int* __restrict__ offsets,
                                           const int* __restrict__ edge_ids,
                                           float* __restrict__ out, int n_nodes) {
    int t = blockIdx.x * blockDim.x + threadIdx.x;
    int r = t >> 5;
    int c = (t & 31) << 2;
    if (r >= n_nodes) return;

    size_t base = (size_t)r * NFEAT + c;
    float4 acc = *reinterpret_cast<const float4*>(node_att + base);

    int beg = offsets[r];
    int end = offsets[r + 1];
    for (int i = beg; i < end; ++i) {
        int e = edge_ids[i];
        int s = src[e];
        float4 ea = *reinterpret_cast<const float4*>(edge_att + (size_t)e * NFEAT + c);
        float4 na = *reinterpret_cast<const float4*>(node_att + (size_t)s * NFEAT + c);
        acc.x += ea.x * na.x;
        acc.y += ea.y * na.y;
        acc.z += ea.z * na.z;
        acc.w += ea.w * na.w;
    }

    float m = fmaxf(fmaxf(acc.x, acc.y), fmaxf(acc.z, acc.w));
    #pragma unroll
    for (int off = 16; off > 0; off >>= 1)
        m = fmaxf(m, __shfl_xor(m, off, 32));

    acc.x = __expf(acc.x - m); acc.y = __expf(acc.y - m);
    acc.z = __expf(acc.z - m); acc.w = __expf(acc.w - m);

    float s = acc.x + acc.y + acc.z + acc.w;
    #pragma unroll
    for (int off = 16; off > 0; off >>= 1)
        s += __shfl_xor(s, off, 32);

    float inv = 1.0f / s;
    acc.x *= inv; acc.y *= inv; acc.z *= inv; acc.w *= inv;
    *reinterpret_cast<float4*>(out + base) = acc;
}

// ---------------------------------------------------------------------------
// K3: new_edge_att = softmax(new_node[src]*new_node[dst] + edge_att, axis=1)
// ---------------------------------------------------------------------------
__global__ void edge_softmax_kernel(const float* __restrict__ new_node,
                                    const float* __restrict__ edge_att,
                                    const int* __restrict__ src,
                                    const int* __restrict__ dst,
                                    float* __restrict__ out, int n_edges) {
    int t = blockIdx.x * blockDim.x + threadIdx.x;
    int e = t >> 5;
    int c = (t & 31) << 2;
    if (e >= n_edges) return;

    int s_i = src[e];
    int d_i = dst[e];

    float4 ns = *reinterpret_cast<const float4*>(new_node + (size_t)s_i * NFEAT + c);
    float4 nd = *reinterpret_cast<const float4*>(new_node + (size_t)d_i * NFEAT + c);
    float4 ea = *reinterpret_cast<const float4*>(edge_att + (size_t)e * NFEAT + c);

    float4 v;
    v.x = ns.x * nd.x + ea.x;
    v.y = ns.y * nd.y + ea.y;
    v.z = ns.z * nd.z + ea.z;
    v.w = ns.w * nd.w + ea.w;

    float m = fmaxf(fmaxf(v.x, v.y), fmaxf(v.z, v.w));
    #pragma unroll
    for (int off = 16; off > 0; off >>= 1)
        m = fmaxf(m, __shfl_xor(m, off, 32));

    v.x = __expf(v.x - m); v.y = __expf(v.y - m);
    v.z = __expf(v.z - m); v.w = __expf(v.w - m);

    float s = v.x + v.y + v.z + v.w;
    #pragma unroll
    for (int off = 16; off > 0; off >>= 1)
        s += __shfl_xor(s, off, 32);

    float inv = 1.0f / s;
    v.x *= inv; v.y *= inv; v.z *= inv; v.w *= inv;
    *reinterpret_cast<float4*>(out + (size_t)e * NFEAT + c) = v;
}

// ---------------------------------------------------------------------------
extern "C" void kernel_launch(void* const* d_in, const int* in_sizes, int n_in,
                              void* d_out, int out_size, void* d_ws, size_t ws_size,
                              hipStream_t stream) {
    const float* node_att = (const float*)d_in[0];
    const float* edge_att = (const float*)d_in[1];
    const int*   src      = (const int*)d_in[2];
    const int*   dst      = (const int*)d_in[3];

    int n_nodes = in_sizes[0] / NFEAT;
    int n_edges = in_sizes[2];

    float* out_node = (float*)d_out;                       // [N, 128]
    float* out_edge = out_node + (size_t)n_nodes * NFEAT;  // [E, 128]

    // workspace layout (ints): counts[N] | offsets[N+1] | cursor[N] | edge_ids[E]
    int* counts   = (int*)d_ws;
    int* offsets  = counts + n_nodes;
    int* cursor   = offsets + (n_nodes + 1);
    int* edge_ids = cursor + n_nodes;

    const int BLK = 256;

    // zero histogram with our own kernel (rocclr fillBuffer was ~250 us!)
    {
        int grid = (n_nodes + BLK - 1) / BLK;
        zero_kernel<<<grid, BLK, 0, stream>>>(counts, n_nodes);
    }

    // CSR build
    {
        int grid = (n_edges + BLK - 1) / BLK;
        hist_kernel<<<grid, BLK, 0, stream>>>(dst, counts, n_edges);
    }
    scan_kernel<<<1, 1024, 0, stream>>>(counts, offsets, cursor, n_nodes);
    {
        int grid = (n_edges + BLK - 1) / BLK;
        fill_kernel<<<grid, BLK, 0, stream>>>(dst, cursor, edge_ids, n_edges);
    }

    // fused segment-sum + node softmax
    {
        long long threads = (long long)n_nodes * 32;
        int grid = (int)((threads + BLK - 1) / BLK);
        node_gather_softmax_kernel<<<grid, BLK, 0, stream>>>(
            node_att, edge_att, src, offsets, edge_ids, out_node, n_nodes);
    }
    // edge softmax
    {
        long long threads = (long long)n_edges * 32;
        int grid = (int)((threads + BLK - 1) / BLK);
        edge_softmax_kernel<<<grid, BLK, 0, stream>>>(
            out_node, edge_att, src, dst, out_edge, n_edges);
    }
}

// Round 4
// 443.072 us; speedup vs baseline: 3.5749x; 1.1510x over previous
//
#include <hip/hip_runtime.h>

#define NFEAT 128

typedef float v4f __attribute__((ext_vector_type(4)));

__device__ __forceinline__ v4f nt_load4(const float* p) {
    return __builtin_nontemporal_load(reinterpret_cast<const v4f*>(p));
}
__device__ __forceinline__ v4f ld4(const float* p) {
    return *reinterpret_cast<const v4f*>(p);
}
__device__ __forceinline__ void nt_store4(float* p, v4f v) {
    __builtin_nontemporal_store(v, reinterpret_cast<v4f*>(p));
}

// ---------------------------------------------------------------------------
// Zero the counts array.
// ---------------------------------------------------------------------------
__global__ void zero_kernel(int* __restrict__ p, int n) {
    int i = blockIdx.x * blockDim.x + threadIdx.x;
    if (i < n) p[i] = 0;
}

// ---------------------------------------------------------------------------
// CSR pass A: histogram of dst
// ---------------------------------------------------------------------------
__global__ void hist_kernel(const int* __restrict__ dst,
                            int* __restrict__ counts, int n_edges) {
    int e = blockIdx.x * blockDim.x + threadIdx.x;
    if (e < n_edges) atomicAdd(&counts[dst[e]], 1);
}

// ---------------------------------------------------------------------------
// CSR pass B: three-kernel scan (multi-block; old single-block version was
// one CU working serially over 49 chunks).
// scan1: per-block (1024-elem) exclusive scan, block totals out.
// scan2: single-wave scan of the <=64 block totals.
// scan3: add block bases, emit offsets + cursor copy + total.
// ---------------------------------------------------------------------------
__global__ void scan1_kernel(const int* __restrict__ counts,
                             int* __restrict__ offsets,
                             int* __restrict__ blocksum, int n) {
    __shared__ int wsum[16];
    int tid  = threadIdx.x;
    int lane = tid & 63;
    int wid  = tid >> 6;
    int i = blockIdx.x * 1024 + tid;
    int v = (i < n) ? counts[i] : 0;

    int x = v;
    #pragma unroll
    for (int off = 1; off < 64; off <<= 1) {
        int y = __shfl_up(x, off, 64);
        if (lane >= off) x += y;
    }
    if (lane == 63) wsum[wid] = x;
    __syncthreads();
    if (tid < 16) {
        int w = wsum[tid];
        #pragma unroll
        for (int off = 1; off < 16; off <<= 1) {
            int y = __shfl_up(w, off, 16);
            if (tid >= off) w += y;
        }
        wsum[tid] = w;
    }
    __syncthreads();
    int waveoff = (wid == 0) ? 0 : wsum[wid - 1];
    if (i < n) offsets[i] = waveoff + x - v;          // block-local exclusive
    if (tid == 1023) blocksum[blockIdx.x] = waveoff + x;
}

__global__ void scan2_kernel(int* __restrict__ blocksum,
                             int* __restrict__ blockoff, int nb) {
    int lane = threadIdx.x;   // single wave of 64, nb <= 64
    int v = (lane < nb) ? blocksum[lane] : 0;
    int x = v;
    #pragma unroll
    for (int off = 1; off < 64; off <<= 1) {
        int y = __shfl_up(x, off, 64);
        if (lane >= off) x += y;
    }
    if (lane < nb) blockoff[lane] = x - v;
    if (lane == nb - 1) blockoff[nb] = x;             // grand total
}

__global__ void scan3_kernel(int* __restrict__ offsets,
                             int* __restrict__ cursor,
                             const int* __restrict__ blockoff,
                             int n, int nb) {
    int i = blockIdx.x * 1024 + threadIdx.x;
    if (i < n) {
        int o = offsets[i] + blockoff[blockIdx.x];
        offsets[i] = o;
        cursor[i]  = o;
    }
    if (i == 0) offsets[n] = blockoff[nb];
}

// ---------------------------------------------------------------------------
// CSR pass C: fill edge id lists
// ---------------------------------------------------------------------------
__global__ void fill_kernel(const int* __restrict__ dst,
                            int* __restrict__ cursor,
                            int* __restrict__ edge_ids, int n_edges) {
    int e = blockIdx.x * blockDim.x + threadIdx.x;
    if (e < n_edges) {
        int pos = atomicAdd(&cursor[dst[e]], 1);
        edge_ids[pos] = e;
    }
}

// ---------------------------------------------------------------------------
// Fused segment-sum + node softmax. One 32-lane group per node row.
// Lane-parallel preload of (edge_id, src) pairs + shfl broadcast: replaces
// the serial dependent-load chain with independent row gathers (high MLP).
// edge_att is read exactly once in random row order -> nontemporal.
// ---------------------------------------------------------------------------
__global__ void node_gather_softmax_kernel(const float* __restrict__ node_att,
                                           const float* __restrict__ edge_att,
                                           const int* __restrict__ src,
                                           const int* __restrict__ offsets,
                                           const int* __restrict__ edge_ids,
                                           float* __restrict__ out, int n_nodes) {
    int t = blockIdx.x * blockDim.x + threadIdx.x;
    int r = t >> 5;
    int lane = t & 31;
    int c = lane << 2;
    if (r >= n_nodes) return;

    size_t base = (size_t)r * NFEAT + c;
    v4f acc = ld4(node_att + base);

    int beg = offsets[r];
    int end = offsets[r + 1];

    for (int tbase = beg; tbase < end; tbase += 32) {
        int li = tbase + lane;
        int e_l = 0, s_l = 0;
        if (li < end) {
            e_l = edge_ids[li];
            s_l = src[e_l];
        }
        int m = min(32, end - tbase);
        #pragma unroll 4
        for (int j = 0; j < m; ++j) {
            int e = __shfl(e_l, j, 32);
            int s = __shfl(s_l, j, 32);
            v4f ea = nt_load4(edge_att + (size_t)e * NFEAT + c);
            v4f na = ld4(node_att + (size_t)s * NFEAT + c);
            acc += ea * na;
        }
    }

    // softmax over the 128-feature row
    float m4 = fmaxf(fmaxf(acc.x, acc.y), fmaxf(acc.z, acc.w));
    #pragma unroll
    for (int off = 16; off > 0; off >>= 1)
        m4 = fmaxf(m4, __shfl_xor(m4, off, 32));

    acc.x = __expf(acc.x - m4); acc.y = __expf(acc.y - m4);
    acc.z = __expf(acc.z - m4); acc.w = __expf(acc.w - m4);

    float s = acc.x + acc.y + acc.z + acc.w;
    #pragma unroll
    for (int off = 16; off > 0; off >>= 1)
        s += __shfl_xor(s, off, 32);

    float inv = 1.0f / s;
    acc *= inv;
    *reinterpret_cast<v4f*>(out + base) = acc;   // re-read by K3: cached store
}

// ---------------------------------------------------------------------------
// K3: new_edge_att = softmax(new_node[src]*new_node[dst] + edge_att, axis=1)
// edge_att streamed once -> NT load; out never re-read -> NT store.
// Keeps the hot 25.6 MB new_node table resident in L2 for the gathers.
// ---------------------------------------------------------------------------
__global__ void edge_softmax_kernel(const float* __restrict__ new_node,
                                    const float* __restrict__ edge_att,
                                    const int* __restrict__ src,
                                    const int* __restrict__ dst,
                                    float* __restrict__ out, int n_edges) {
    int t = blockIdx.x * blockDim.x + threadIdx.x;
    int e = t >> 5;
    int c = (t & 31) << 2;
    if (e >= n_edges) return;

    int s_i = src[e];
    int d_i = dst[e];

    v4f ns = ld4(new_node + (size_t)s_i * NFEAT + c);
    v4f nd = ld4(new_node + (size_t)d_i * NFEAT + c);
    v4f ea = nt_load4(edge_att + (size_t)e * NFEAT + c);

    v4f v = ns * nd + ea;

    float m = fmaxf(fmaxf(v.x, v.y), fmaxf(v.z, v.w));
    #pragma unroll
    for (int off = 16; off > 0; off >>= 1)
        m = fmaxf(m, __shfl_xor(m, off, 32));

    v.x = __expf(v.x - m); v.y = __expf(v.y - m);
    v.z = __expf(v.z - m); v.w = __expf(v.w - m);

    float s = v.x + v.y + v.z + v.w;
    #pragma unroll
    for (int off = 16; off > 0; off >>= 1)
        s += __shfl_xor(s, off, 32);

    float inv = 1.0f / s;
    v *= inv;
    nt_store4(out + (size_t)e * NFEAT + c, v);
}

// ---------------------------------------------------------------------------
extern "C" void kernel_launch(void* const* d_in, const int* in_sizes, int n_in,
                              void* d_out, int out_size, void* d_ws, size_t ws_size,
                              hipStream_t stream) {
    const float* node_att = (const float*)d_in[0];
    const float* edge_att = (const float*)d_in[1];
    const int*   src      = (const int*)d_in[2];
    const int*   dst      = (const int*)d_in[3];

    int n_nodes = in_sizes[0] / NFEAT;
    int n_edges = in_sizes[2];

    float* out_node = (float*)d_out;                       // [N, 128]
    float* out_edge = out_node + (size_t)n_nodes * NFEAT;  // [E, 128]

    // ws layout (ints): counts[N] | offsets[N+1] | cursor[N] | edge_ids[E] |
    //                   blocksum[64] | blockoff[65]
    int* counts   = (int*)d_ws;
    int* offsets  = counts + n_nodes;
    int* cursor   = offsets + (n_nodes + 1);
    int* edge_ids = cursor + n_nodes;
    int* blocksum = edge_ids + n_edges;
    int* blockoff = blocksum + 64;

    const int BLK = 256;
    int nb = (n_nodes + 1023) / 1024;   // scan blocks (49 for 50k)

    {   // zero histogram
        int grid = (n_nodes + BLK - 1) / BLK;
        zero_kernel<<<grid, BLK, 0, stream>>>(counts, n_nodes);
    }
    {   // histogram
        int grid = (n_edges + BLK - 1) / BLK;
        hist_kernel<<<grid, BLK, 0, stream>>>(dst, counts, n_edges);
    }
    // 3-kernel scan
    scan1_kernel<<<nb, 1024, 0, stream>>>(counts, offsets, blocksum, n_nodes);
    scan2_kernel<<<1, 64, 0, stream>>>(blocksum, blockoff, nb);
    scan3_kernel<<<nb, 1024, 0, stream>>>(offsets, cursor, blockoff, n_nodes, nb);
    {   // fill edge lists
        int grid = (n_edges + BLK - 1) / BLK;
        fill_kernel<<<grid, BLK, 0, stream>>>(dst, cursor, edge_ids, n_edges);
    }
    {   // fused segment-sum + node softmax
        long long threads = (long long)n_nodes * 32;
        int grid = (int)((threads + BLK - 1) / BLK);
        node_gather_softmax_kernel<<<grid, BLK, 0, stream>>>(
            node_att, edge_att, src, offsets, edge_ids, out_node, n_nodes);
    }
    {   // edge softmax
        long long threads = (long long)n_edges * 32;
        int grid = (int)((threads + BLK - 1) / BLK);
        edge_softmax_kernel<<<grid, BLK, 0, stream>>>(
            out_node, edge_att, src, dst, out_edge, n_edges);
    }
}

// Round 8
// 432.262 us; speedup vs baseline: 3.6643x; 1.0250x over previous
//
#include <hip/hip_runtime.h>

#define NFEAT 128

typedef float v4f __attribute__((ext_vector_type(4)));

__device__ __forceinline__ v4f nt_load4(const float* p) {
    return __builtin_nontemporal_load(reinterpret_cast<const v4f*>(p));
}
__device__ __forceinline__ v4f ld4(const float* p) {
    return *reinterpret_cast<const v4f*>(p);
}
__device__ __forceinline__ void nt_store4(float* p, v4f v) {
    __builtin_nontemporal_store(v, reinterpret_cast<v4f*>(p));
}

// Bijective XCD swizzle (m204 form): HW assigns blocks round-robin to the 8
// XCDs; remap so each XCD owns a CONTIGUOUS chunk of logical work -> shared
// rows/lines stay in one XCD's L2.
__device__ __forceinline__ int xcd_swizzle(int wg, int nwg) {
    const int NX = 8;
    int q = nwg / NX, r = nwg % NX;
    int xcd = wg % NX, idx = wg / NX;
    int base = (xcd < r) ? xcd * (q + 1) : r * (q + 1) + (xcd - r) * q;
    return base + idx;
}

// ---------------------------------------------------------------------------
__global__ void zero_kernel(int* __restrict__ p, int n) {
    int i = blockIdx.x * blockDim.x + threadIdx.x;
    if (i < n) p[i] = 0;
}

// ---------------------------------------------------------------------------
// CSR pass A: histogram of dst
// ---------------------------------------------------------------------------
__global__ void hist_kernel(const int* __restrict__ dst,
                            int* __restrict__ counts, int n_edges) {
    int e = blockIdx.x * blockDim.x + threadIdx.x;
    if (e < n_edges) atomicAdd(&counts[dst[e]], 1);
}

// ---------------------------------------------------------------------------
// CSR pass B: three-kernel multi-block scan
// ---------------------------------------------------------------------------
__global__ void scan1_kernel(const int* __restrict__ counts,
                             int* __restrict__ offsets,
                             int* __restrict__ blocksum, int n) {
    __shared__ int wsum[16];
    int tid  = threadIdx.x;
    int lane = tid & 63;
    int wid  = tid >> 6;
    int i = blockIdx.x * 1024 + tid;
    int v = (i < n) ? counts[i] : 0;

    int x = v;
    #pragma unroll
    for (int off = 1; off < 64; off <<= 1) {
        int y = __shfl_up(x, off, 64);
        if (lane >= off) x += y;
    }
    if (lane == 63) wsum[wid] = x;
    __syncthreads();
    if (tid < 16) {
        int w = wsum[tid];
        #pragma unroll
        for (int off = 1; off < 16; off <<= 1) {
            int y = __shfl_up(w, off, 16);
            if (tid >= off) w += y;
        }
        wsum[tid] = w;
    }
    __syncthreads();
    int waveoff = (wid == 0) ? 0 : wsum[wid - 1];
    if (i < n) offsets[i] = waveoff + x - v;
    if (tid == 1023) blocksum[blockIdx.x] = waveoff + x;
}

__global__ void scan2_kernel(int* __restrict__ blocksum,
                             int* __restrict__ blockoff, int nb) {
    int lane = threadIdx.x;   // single wave of 64, nb <= 64
    int v = (lane < nb) ? blocksum[lane] : 0;
    int x = v;
    #pragma unroll
    for (int off = 1; off < 64; off <<= 1) {
        int y = __shfl_up(x, off, 64);
        if (lane >= off) x += y;
    }
    if (lane < nb) blockoff[lane] = x - v;
    if (lane == nb - 1) blockoff[nb] = x;
}

__global__ void scan3_kernel(int* __restrict__ offsets,
                             int* __restrict__ cursor,
                             const int* __restrict__ blockoff,
                             int n, int nb) {
    int i = blockIdx.x * 1024 + threadIdx.x;
    if (i < n) {
        int o = offsets[i] + blockoff[blockIdx.x];
        offsets[i] = o;
        cursor[i]  = o;
    }
    if (i == 0) offsets[n] = blockoff[nb];
}

// ---------------------------------------------------------------------------
// CSR pass C: fill edge id lists
// ---------------------------------------------------------------------------
__global__ void fill_kernel(const int* __restrict__ dst,
                            int* __restrict__ cursor,
                            int* __restrict__ edge_ids, int n_edges) {
    int e = blockIdx.x * blockDim.x + threadIdx.x;
    if (e < n_edges) {
        int pos = atomicAdd(&cursor[dst[e]], 1);
        edge_ids[pos] = e;
    }
}

// ---------------------------------------------------------------------------
// Fused segment-sum + node softmax. One 32-lane group per node row.
// Lane-parallel (edge_id, src) preload + shfl broadcast for MLP.
// ---------------------------------------------------------------------------
__global__ void node_gather_softmax_kernel(const float* __restrict__ node_att,
                                           const float* __restrict__ edge_att,
                                           const int* __restrict__ src,
                                           const int* __restrict__ offsets,
                                           const int* __restrict__ edge_ids,
                                           float* __restrict__ out, int n_nodes) {
    int t = blockIdx.x * blockDim.x + threadIdx.x;
    int r = t >> 5;
    int lane = t & 31;
    int c = lane << 2;
    if (r >= n_nodes) return;

    size_t base = (size_t)r * NFEAT + c;
    v4f acc = ld4(node_att + base);

    int beg = offsets[r];
    int end = offsets[r + 1];

    for (int tbase = beg; tbase < end; tbase += 32) {
        int li = tbase + lane;
        int e_l = 0, s_l = 0;
        if (li < end) {
            e_l = edge_ids[li];
            s_l = src[e_l];
        }
        int m = min(32, end - tbase);
        #pragma unroll 4
        for (int j = 0; j < m; ++j) {
            int e = __shfl(e_l, j, 32);
            int s = __shfl(s_l, j, 32);
            v4f ea = nt_load4(edge_att + (size_t)e * NFEAT + c);
            v4f na = ld4(node_att + (size_t)s * NFEAT + c);
            acc += ea * na;
        }
    }

    float m4 = fmaxf(fmaxf(acc.x, acc.y), fmaxf(acc.z, acc.w));
    #pragma unroll
    for (int off = 16; off > 0; off >>= 1)
        m4 = fmaxf(m4, __shfl_xor(m4, off, 32));

    acc.x = __expf(acc.x - m4); acc.y = __expf(acc.y - m4);
    acc.z = __expf(acc.z - m4); acc.w = __expf(acc.w - m4);

    float s = acc.x + acc.y + acc.z + acc.w;
    #pragma unroll
    for (int off = 16; off > 0; off >>= 1)
        s += __shfl_xor(s, off, 32);

    float inv = 1.0f / s;
    acc *= inv;
    *reinterpret_cast<v4f*>(out + base) = acc;   // re-read by K3: cached store
}

// ---------------------------------------------------------------------------
// K3 (CSR-ordered): iterate CSR positions i; e = edge_ids[i]. Consecutive
// groups share the same dst row -> nd gather becomes an L1/L2 hit instead of
// an L3 round-trip. XCD swizzle keeps consecutive positions on one XCD.
// Output rows are scattered but full 512 B lines (NT store).
// ---------------------------------------------------------------------------
__global__ void edge_softmax_kernel(const float* __restrict__ new_node,
                                    const float* __restrict__ edge_att,
                                    const int* __restrict__ src,
                                    const int* __restrict__ dst,
                                    const int* __restrict__ edge_ids,
                                    float* __restrict__ out, int n_edges) {
    int wg = xcd_swizzle(blockIdx.x, gridDim.x);
    int t = wg * blockDim.x + threadIdx.x;
    int i = t >> 5;
    int c = (t & 31) << 2;
    if (i >= n_edges) return;

    int e   = edge_ids[i];
    int s_i = src[e];
    int d_i = dst[e];

    v4f ns = ld4(new_node + (size_t)s_i * NFEAT + c);
    v4f nd = ld4(new_node + (size_t)d_i * NFEAT + c);
    v4f ea = nt_load4(edge_att + (size_t)e * NFEAT + c);

    v4f v = ns * nd + ea;

    float m = fmaxf(fmaxf(v.x, v.y), fmaxf(v.z, v.w));
    #pragma unroll
    for (int off = 16; off > 0; off >>= 1)
        m = fmaxf(m, __shfl_xor(m, off, 32));

    v.x = __expf(v.x - m); v.y = __expf(v.y - m);
    v.z = __expf(v.z - m); v.w = __expf(v.w - m);

    float s = v.x + v.y + v.z + v.w;
    #pragma unroll
    for (int off = 16; off > 0; off >>= 1)
        s += __shfl_xor(s, off, 32);

    float inv = 1.0f / s;
    v *= inv;
    nt_store4(out + (size_t)e * NFEAT + c, v);
}

// ---------------------------------------------------------------------------
extern "C" void kernel_launch(void* const* d_in, const int* in_sizes, int n_in,
                              void* d_out, int out_size, void* d_ws, size_t ws_size,
                              hipStream_t stream) {
    const float* node_att = (const float*)d_in[0];
    const float* edge_att = (const float*)d_in[1];
    const int*   src      = (const int*)d_in[2];
    const int*   dst      = (const int*)d_in[3];

    int n_nodes = in_sizes[0] / NFEAT;
    int n_edges = in_sizes[2];

    float* out_node = (float*)d_out;                       // [N, 128]
    float* out_edge = out_node + (size_t)n_nodes * NFEAT;  // [E, 128]

    // ws layout (ints): counts[N] | offsets[N+1] | cursor[N] | edge_ids[E] |
    //                   blocksum[64] | blockoff[65]
    int* counts   = (int*)d_ws;
    int* offsets  = counts + n_nodes;
    int* cursor   = offsets + (n_nodes + 1);
    int* edge_ids = cursor + n_nodes;
    int* blocksum = edge_ids + n_edges;
    int* blockoff = blocksum + 64;

    const int BLK = 256;
    int nb = (n_nodes + 1023) / 1024;

    {   // zero histogram
        int grid = (n_nodes + BLK - 1) / BLK;
        zero_kernel<<<grid, BLK, 0, stream>>>(counts, n_nodes);
    }
    {   // histogram
        int grid = (n_edges + BLK - 1) / BLK;
        hist_kernel<<<grid, BLK, 0, stream>>>(dst, counts, n_edges);
    }
    scan1_kernel<<<nb, 1024, 0, stream>>>(counts, offsets, blocksum, n_nodes);
    scan2_kernel<<<1, 64, 0, stream>>>(blocksum, blockoff, nb);
    scan3_kernel<<<nb, 1024, 0, stream>>>(offsets, cursor, blockoff, n_nodes, nb);
    {   // fill edge lists
        int grid = (n_edges + BLK - 1) / BLK;
        fill_kernel<<<grid, BLK, 0, stream>>>(dst, cursor, edge_ids, n_edges);
    }
    {   // fused segment-sum + node softmax
        long long threads = (long long)n_nodes * 32;
        int grid = (int)((threads + BLK - 1) / BLK);
        node_gather_softmax_kernel<<<grid, BLK, 0, stream>>>(
            node_att, edge_att, src, offsets, edge_ids, out_node, n_nodes);
    }
    {   // edge softmax in dst-CSR order
        long long threads = (long long)n_edges * 32;
        int grid = (int)((threads + BLK - 1) / BLK);
        edge_softmax_kernel<<<grid, BLK, 0, stream>>>(
            out_node, edge_att, src, dst, edge_ids, out_edge, n_edges);
    }
}

// Round 9
// 412.368 us; speedup vs baseline: 3.8410x; 1.0482x over previous
//
#include <hip/hip_runtime.h>

#define NFEAT 128

typedef float v4f __attribute__((ext_vector_type(4)));

__device__ __forceinline__ v4f nt_load4(const float* p) {
    return __builtin_nontemporal_load(reinterpret_cast<const v4f*>(p));
}
__device__ __forceinline__ v4f ld4(const float* p) {
    return *reinterpret_cast<const v4f*>(p);
}
__device__ __forceinline__ void nt_store4(float* p, v4f v) {
    __builtin_nontemporal_store(v, reinterpret_cast<v4f*>(p));
}

// Bijective XCD swizzle (m204 form).
__device__ __forceinline__ int xcd_swizzle(int wg, int nwg) {
    const int NX = 8;
    int q = nwg / NX, r = nwg % NX;
    int xcd = wg % NX, idx = wg / NX;
    int base = (xcd < r) ? xcd * (q + 1) : r * (q + 1) + (xcd - r) * q;
    return base + idx;
}

// ---------------------------------------------------------------------------
__global__ void zero_kernel(int* __restrict__ p, int n) {
    int i = blockIdx.x * blockDim.x + threadIdx.x;
    if (i < n) p[i] = 0;
}

// ---------------------------------------------------------------------------
// CSR pass A: histogram of dst
// ---------------------------------------------------------------------------
__global__ void hist_kernel(const int* __restrict__ dst,
                            int* __restrict__ counts, int n_edges) {
    int e = blockIdx.x * blockDim.x + threadIdx.x;
    if (e < n_edges) atomicAdd(&counts[dst[e]], 1);
}

// ---------------------------------------------------------------------------
// CSR pass B: three-kernel multi-block scan
// ---------------------------------------------------------------------------
__global__ void scan1_kernel(const int* __restrict__ counts,
                             int* __restrict__ offsets,
                             int* __restrict__ blocksum, int n) {
    __shared__ int wsum[16];
    int tid  = threadIdx.x;
    int lane = tid & 63;
    int wid  = tid >> 6;
    int i = blockIdx.x * 1024 + tid;
    int v = (i < n) ? counts[i] : 0;

    int x = v;
    #pragma unroll
    for (int off = 1; off < 64; off <<= 1) {
        int y = __shfl_up(x, off, 64);
        if (lane >= off) x += y;
    }
    if (lane == 63) wsum[wid] = x;
    __syncthreads();
    if (tid < 16) {
        int w = wsum[tid];
        #pragma unroll
        for (int off = 1; off < 16; off <<= 1) {
            int y = __shfl_up(w, off, 16);
            if (tid >= off) w += y;
        }
        wsum[tid] = w;
    }
    __syncthreads();
    int waveoff = (wid == 0) ? 0 : wsum[wid - 1];
    if (i < n) offsets[i] = waveoff + x - v;
    if (tid == 1023) blocksum[blockIdx.x] = waveoff + x;
}

__global__ void scan2_kernel(int* __restrict__ blocksum,
                             int* __restrict__ blockoff, int nb) {
    int lane = threadIdx.x;   // single wave of 64, nb <= 64
    int v = (lane < nb) ? blocksum[lane] : 0;
    int x = v;
    #pragma unroll
    for (int off = 1; off < 64; off <<= 1) {
        int y = __shfl_up(x, off, 64);
        if (lane >= off) x += y;
    }
    if (lane < nb) blockoff[lane] = x - v;
    if (lane == nb - 1) blockoff[nb] = x;
}

__global__ void scan3_kernel(int* __restrict__ offsets,
                             int* __restrict__ cursor,
                             const int* __restrict__ blockoff,
                             int n, int nb) {
    int i = blockIdx.x * 1024 + threadIdx.x;
    if (i < n) {
        int o = offsets[i] + blockoff[blockIdx.x];
        offsets[i] = o;
        cursor[i]  = o;
    }
    if (i == 0) offsets[n] = blockoff[nb];
}

// ---------------------------------------------------------------------------
// CSR pass C: fill PACKED (edge, src, dst) triples per CSR position.
// Consumers then need exactly one 16B load — no dependent index chains.
// ---------------------------------------------------------------------------
__global__ void fill_kernel(const int* __restrict__ dst,
                            const int* __restrict__ src,
                            int* __restrict__ cursor,
                            int4* __restrict__ pairs, int n_edges) {
    int e = blockIdx.x * blockDim.x + threadIdx.x;
    if (e < n_edges) {
        int d = dst[e];
        int s = src[e];
        int pos = atomicAdd(&cursor[d], 1);
        pairs[pos] = make_int4(e, s, d, 0);
    }
}

// ---------------------------------------------------------------------------
// Fused segment-sum + node softmax. One 32-lane group per node row.
// Lane-parallel int4 tile preload + shfl broadcast; unroll 8 for MLP.
// ---------------------------------------------------------------------------
__global__ void node_gather_softmax_kernel(const float* __restrict__ node_att,
                                           const float* __restrict__ edge_att,
                                           const int4* __restrict__ pairs,
                                           const int* __restrict__ offsets,
                                           float* __restrict__ out, int n_nodes) {
    int t = blockIdx.x * blockDim.x + threadIdx.x;
    int r = t >> 5;
    int lane = t & 31;
    int c = lane << 2;
    if (r >= n_nodes) return;

    size_t base = (size_t)r * NFEAT + c;
    v4f acc = ld4(node_att + base);

    int beg = offsets[r];
    int end = offsets[r + 1];

    for (int tbase = beg; tbase < end; tbase += 32) {
        int li = tbase + lane;
        int e_l = 0, s_l = 0;
        if (li < end) {
            int4 p = pairs[li];          // one coalesced 16B load per lane
            e_l = p.x; s_l = p.y;
        }
        int m = min(32, end - tbase);
        #pragma unroll 8
        for (int j = 0; j < m; ++j) {
            int e = __shfl(e_l, j, 32);
            int s = __shfl(s_l, j, 32);
            v4f ea = nt_load4(edge_att + (size_t)e * NFEAT + c);
            v4f na = ld4(node_att + (size_t)s * NFEAT + c);
            acc += ea * na;
        }
    }

    float m4 = fmaxf(fmaxf(acc.x, acc.y), fmaxf(acc.z, acc.w));
    #pragma unroll
    for (int off = 16; off > 0; off >>= 1)
        m4 = fmaxf(m4, __shfl_xor(m4, off, 32));

    acc.x = __expf(acc.x - m4); acc.y = __expf(acc.y - m4);
    acc.z = __expf(acc.z - m4); acc.w = __expf(acc.w - m4);

    float s = acc.x + acc.y + acc.z + acc.w;
    #pragma unroll
    for (int off = 16; off > 0; off >>= 1)
        s += __shfl_xor(s, off, 32);

    float inv = 1.0f / s;
    acc *= inv;
    *reinterpret_cast<v4f*>(out + base) = acc;   // re-read by K3: cached store
}

// ---------------------------------------------------------------------------
// K3 (CSR-ordered): one 16B broadcast load gives (e, src, dst). Consecutive
// groups share the same dst row (avg degree 16) -> nd gather L1/L2-hit.
// ---------------------------------------------------------------------------
__global__ void edge_softmax_kernel(const float* __restrict__ new_node,
                                    const float* __restrict__ edge_att,
                                    const int4* __restrict__ pairs,
                                    float* __restrict__ out, int n_edges) {
    int wg = xcd_swizzle(blockIdx.x, gridDim.x);
    int t = wg * blockDim.x + threadIdx.x;
    int i = t >> 5;
    int c = (t & 31) << 2;
    if (i >= n_edges) return;

    int4 p  = pairs[i];                  // broadcast: same addr for 32 lanes
    int e   = p.x;
    int s_i = p.y;
    int d_i = p.z;

    v4f ns = ld4(new_node + (size_t)s_i * NFEAT + c);
    v4f nd = ld4(new_node + (size_t)d_i * NFEAT + c);
    v4f ea = nt_load4(edge_att + (size_t)e * NFEAT + c);

    v4f v = ns * nd + ea;

    float m = fmaxf(fmaxf(v.x, v.y), fmaxf(v.z, v.w));
    #pragma unroll
    for (int off = 16; off > 0; off >>= 1)
        m = fmaxf(m, __shfl_xor(m, off, 32));

    v.x = __expf(v.x - m); v.y = __expf(v.y - m);
    v.z = __expf(v.z - m); v.w = __expf(v.w - m);

    float s = v.x + v.y + v.z + v.w;
    #pragma unroll
    for (int off = 16; off > 0; off >>= 1)
        s += __shfl_xor(s, off, 32);

    float inv = 1.0f / s;
    v *= inv;
    nt_store4(out + (size_t)e * NFEAT + c, v);
}

// ---------------------------------------------------------------------------
extern "C" void kernel_launch(void* const* d_in, const int* in_sizes, int n_in,
                              void* d_out, int out_size, void* d_ws, size_t ws_size,
                              hipStream_t stream) {
    const float* node_att = (const float*)d_in[0];
    const float* edge_att = (const float*)d_in[1];
    const int*   src      = (const int*)d_in[2];
    const int*   dst      = (const int*)d_in[3];

    int n_nodes = in_sizes[0] / NFEAT;
    int n_edges = in_sizes[2];

    float* out_node = (float*)d_out;                       // [N, 128]
    float* out_edge = out_node + (size_t)n_nodes * NFEAT;  // [E, 128]

    // ws layout: pairs[E] (int4, 16B-aligned first) | counts[N] | offsets[N+1]
    //            | cursor[N] | blocksum[64] | blockoff[65]
    int4* pairs   = (int4*)d_ws;
    int* counts   = (int*)(pairs + n_edges);
    int* offsets  = counts + n_nodes;
    int* cursor   = offsets + (n_nodes + 1);
    int* blocksum = cursor + n_nodes;
    int* blockoff = blocksum + 64;

    const int BLK = 256;
    int nb = (n_nodes + 1023) / 1024;

    {   // zero histogram
        int grid = (n_nodes + BLK - 1) / BLK;
        zero_kernel<<<grid, BLK, 0, stream>>>(counts, n_nodes);
    }
    {   // histogram
        int grid = (n_edges + BLK - 1) / BLK;
        hist_kernel<<<grid, BLK, 0, stream>>>(dst, counts, n_edges);
    }
    scan1_kernel<<<nb, 1024, 0, stream>>>(counts, offsets, blocksum, n_nodes);
    scan2_kernel<<<1, 64, 0, stream>>>(blocksum, blockoff, nb);
    scan3_kernel<<<nb, 1024, 0, stream>>>(offsets, cursor, blockoff, n_nodes, nb);
    {   // fill packed triples
        int grid = (n_edges + BLK - 1) / BLK;
        fill_kernel<<<grid, BLK, 0, stream>>>(dst, src, cursor, pairs, n_edges);
    }
    {   // fused segment-sum + node softmax
        long long threads = (long long)n_nodes * 32;
        int grid = (int)((threads + BLK - 1) / BLK);
        node_gather_softmax_kernel<<<grid, BLK, 0, stream>>>(
            node_att, edge_att, pairs, offsets, out_node, n_nodes);
    }
    {   // edge softmax in dst-CSR order
        long long threads = (long long)n_edges * 32;
        int grid = (int)((threads + BLK - 1) / BLK);
        edge_softmax_kernel<<<grid, BLK, 0, stream>>>(
            out_node, edge_att, pairs, out_edge, n_edges);
    }
}